// Round 7
// baseline (325.193 us; speedup 1.0000x reference)
//
#include <hip/hip_runtime.h>
#include <hip/hip_fp16.h>

typedef unsigned short u16;
typedef unsigned int   u32;

#define N_MESH 50000
#define RA     40      // R*A
#define F_     32
#define OT     256     // O*T
#define KSELF  1280    // RA*F
#define KTOT   1312    // RA*F + F  (= 41*32 exactly)
#define NCH    41      // K chunks of 32
#define GN     32      // mesh rows per block (2 row-tiles of 16)
#define NBLK   1563    // ceil(50000/32); last block has 16 valid rows
#define SECC   8       // chunks per LDS section
#define NSEC   6       // sections: 8,8,8,8,8,1
#define MESH16_BLOCKS 782   // ceil(200000/256)
#define WEFF_BLOCKS   1312  // ceil(335872/256)

using f32x4 = __attribute__((ext_vector_type(4))) float;
using f16x8 = __attribute__((ext_vector_type(8))) _Float16;   // 8 f16 (4 VGPRs)

// Device-global scratch / flags (no dependence on ws_size).
__device__ __align__(16) u16 g_bhi[NCH * 16 * 64 * 8];      // B frags hi (f16), 672 KB
__device__ __align__(16) u16 g_blo[NCH * 16 * 64 * 8];      // B frags lo (f16), 672 KB
__device__ __align__(16) u16 g_mesh16[N_MESH * F_];         // fp16 mesh shadow, 3.2 MB
__device__ int g_isf32;

__device__ __forceinline__ float bf2f(u16 u) {
    union { u32 i; float f; } v; v.i = ((u32)u) << 16; return v.f;
}
__device__ __forceinline__ u16 f2bf(float f) {
    union { float f; u32 i; } v; v.f = f; u32 u = v.i;
    return (u16)((u + 0x7FFFu + ((u >> 16) & 1u)) >> 16);   // RNE
}
__device__ __forceinline__ float ld(const void* p, int i, int isf32) {
    return isf32 ? ((const float*)p)[i] : bf2f(((const u16*)p)[i]);
}

// ---------------------------------------------------------------------------
// Dtype probe (parallelized): decode first 4096 u16 of mesh_signal as bf16.
// ---------------------------------------------------------------------------
__global__ void detect_kernel(const void* mesh) {
    __shared__ int s_weird;
    if (threadIdx.x == 0) s_weird = 0;
    __syncthreads();
    const u16* p = (const u16*)mesh;
    int w = 0;
    for (int j = threadIdx.x * 16; j < threadIdx.x * 16 + 16; ++j) {
        float v = bf2f(p[j]);
        float a = v < 0.f ? -v : v;
        if (!(a <= 1.0e6f)) ++w;
        else if (a > 0.f && a < 1.0e-30f) ++w;
    }
    atomicAdd(&s_weird, w);
    __syncthreads();
    if (threadIdx.x == 0) g_isf32 = (s_weird > 100) ? 1 : 0;
}

// ---------------------------------------------------------------------------
// Fused prep kernel (one launch instead of two):
//  blocks [0, MESH16_BLOCKS)      : fp16 mesh shadow (3.2 MB, L2-resident;
//                                   round 5: FETCH 273MB -> 107MB)
//  blocks [MESH16_BLOCKS, +WEFF)  : Weff + f16 hi/lo B-fragment pack.
//   k <  1280 : w = sum_ra kernel[ra][k>>5] * W_neighbor[t][r][(a+o)&7][k&31]
//   k >= 1280 : w = W_self[t][k-1280]
//   B-frag layout (mfma_f32_16x16x32 B): lane l, elem e <-> B[k=(l>>4)*8+e][col=l&15]
// ---------------------------------------------------------------------------
__global__ void prep_kernel(const void* __restrict__ mesh,
                            const void* __restrict__ Wn,
                            const void* __restrict__ Wself,
                            const void* __restrict__ ker) {
    const int isf32 = g_isf32;
    if (blockIdx.x < MESH16_BLOCKS) {
        int i = blockIdx.x * 256 + threadIdx.x;   // one thread per 8 elems
        if (i >= N_MESH * F_ / 8) return;
        union { uint4 v; _Float16 h[8]; } o;
        #pragma unroll
        for (int j = 0; j < 8; ++j)
            o.h[j] = (_Float16)ld(mesh, i * 8 + j, isf32);
        *((uint4*)g_mesh16 + i) = o.v;
    } else {
        int e = (blockIdx.x - MESH16_BLOCKS) * 256 + threadIdx.x;
        if (e >= OT * KTOT) return;
        int c = e / KTOT;
        int k = e - c * KTOT;
        int t = c & 31;
        float acc = 0.f;
        if (k < KSELF) {
            int xy = k >> 5, f = k & 31;
            int o = c >> 5;
            for (int ra = 0; ra < RA; ++ra) {
                int r = ra >> 3, a = ra & 7;
                int a2 = (a + o) & 7;
                acc += ld(ker, ra * RA + xy, isf32) *
                       ld(Wn, t * (5 * 8 * F_) + r * (8 * F_) + a2 * F_ + f, isf32);
            }
        } else {
            acc = ld(Wself, t * F_ + (k - KSELF), isf32);
        }
        int ch = k >> 5;
        int kg = (k >> 3) & 3;
        int el = k & 7;
        int nt = c >> 4, col = c & 15;
        size_t fi = ((size_t)(ch * 16 + nt) * 64 + (kg * 16 + col)) * 8 + el;
        union { _Float16 h; u16 u; } H, L;
        H.h = (_Float16)acc;
        L.h = (_Float16)(acc - (float)H.h);
        g_bhi[fi] = H.u;
        g_blo[fi] = L.u;
    }
}

// ---------------------------------------------------------------------------
// Main kernel. Per block: 32 mesh rows (2 row-tiles) x 256 outputs.
// 3-deep software pipeline over the NSEC=6 K-sections (T14 async-stage):
//   during MFMA(s): rows for s+1 and bary for s+2 are in flight as register
//   loads; interp+LDS-write for s+1 happens after the next barrier.
// All task paths unified via the weight trick: normal (w from bary),
// self chunk (w=(1,0,0), row=own), phantom row (w=0) -> one code path,
// no divergence, LDS write always executes.
// Phase 2: 2x MFMA f16 per (rt,j): A*Bhi + A*Blo (B hi/lo ~ 22-bit Weff).
// launch_bounds(256,3): cap 170 regs (est ~150 live incl. 48 staged + 32 acc).
// NOT (256,8): forced 32 VGPR and spilled acc in round 3 (714us).
// ---------------------------------------------------------------------------
__global__ __launch_bounds__(256, 3)
void ConvIntrinsic_17102559772776_kernel(const void* __restrict__ mesh,
                                         const void* __restrict__ bary,
                                         const void* __restrict__ bias,
                                         void* __restrict__ out) {
    __shared__ __align__(16) u16 Alds[SECC * 2 * 64 * 8];   // 16 KB (f16 bits)

    const int tid   = threadIdx.x;
    const int n0    = blockIdx.x * GN;
    const int isf32 = g_isf32;
    const int lane  = tid & 63;
    const int wv    = tid >> 6;    // 0..3 : wave owns N-tiles wv*4 .. wv*4+3
    const int clt   = tid >> 5;    // phase-1 chunk-local 0..7
    const int tn    = tid & 31;    // phase-1 row within block
    const int gn    = n0 + tn;
    const int rt1   = tn >> 4, lr = tn & 15;
    u16* const dst0 = Alds + ((size_t)(clt * 2 + rt1) * 64 + lr) * 8;  // +kg*128

    f32x4 acc[2][4];
    #pragma unroll
    for (int rt = 0; rt < 2; ++rt)
        #pragma unroll
        for (int j = 0; j < 4; ++j) acc[rt][j] = (f32x4){0.f, 0.f, 0.f, 0.f};

    // ---- pipeline staging registers (statically indexed only) ----
    uint2 ba, bb, bc;              // raw bary bytes (fp32: 3x8B; bf16: ba.x,ba.y,bb.x)
    __half2 sw0, sw1, sw2;         // resolved interp weights
    uint4 x0[4], x1[4], x2[4];     // pending mesh rows (48 VGPRs)

    // issue raw bary loads for section s (no decode -> no wait)
    auto bary_issue = [&](int s) {
        if (s >= NSEC) return;
        int nch = (s < NSEC - 1) ? SECC : 1;
        int ch  = s * SECC + clt;
        if (clt >= nch || gn >= N_MESH || ch >= RA) return;
        if (isf32) {
            const uint2* bp = (const uint2*)((const float*)bary + (size_t)gn * (RA * 6) + ch * 6);
            ba = bp[0]; bb = bp[1]; bc = bp[2];
        } else {
            const u32* bp = (const u32*)((const u16*)bary + (size_t)gn * (RA * 6) + ch * 6);
            ba.x = bp[0]; ba.y = bp[1]; bb.x = bp[2];
        }
    };

    // decode bary (waits its loads), resolve mode, issue 12 row loads
    auto rows_issue = [&](int s) {
        if (s >= NSEC) return;
        int nch = (s < NSEC - 1) ? SECC : 1;
        int ch  = s * SECC + clt;
        int i0 = 0, i1 = 0, i2 = 0;
        float w0 = 0.f, w1 = 0.f, w2 = 0.f;
        if (clt < nch && gn < N_MESH) {
            if (ch >= RA) { i0 = gn; w0 = 1.f; }       // self chunk: exact row copy
            else {
                float fi0, fi1, fi2;
                if (isf32) {
                    fi0 = __uint_as_float(ba.x); w0 = __uint_as_float(ba.y);
                    fi1 = __uint_as_float(bb.x); w1 = __uint_as_float(bb.y);
                    fi2 = __uint_as_float(bc.x); w2 = __uint_as_float(bc.y);
                } else {
                    fi0 = bf2f((u16)(ba.x & 0xffffu)); w0 = bf2f((u16)(ba.x >> 16));
                    fi1 = bf2f((u16)(ba.y & 0xffffu)); w1 = bf2f((u16)(ba.y >> 16));
                    fi2 = bf2f((u16)(bb.x & 0xffffu)); w2 = bf2f((u16)(bb.x >> 16));
                }
                i0 = (int)fi0; i1 = (int)fi1; i2 = (int)fi2;
                i0 = i0 < 0 ? 0 : (i0 > N_MESH - 1 ? N_MESH - 1 : i0);
                i1 = i1 < 0 ? 0 : (i1 > N_MESH - 1 ? N_MESH - 1 : i1);
                i2 = i2 < 0 ? 0 : (i2 > N_MESH - 1 ? N_MESH - 1 : i2);
            }
        }
        sw0 = __float2half2_rn(w0);
        sw1 = __float2half2_rn(w1);
        sw2 = __float2half2_rn(w2);
        const uint4* m0 = (const uint4*)g_mesh16 + (size_t)i0 * 4;
        const uint4* m1 = (const uint4*)g_mesh16 + (size_t)i1 * 4;
        const uint4* m2 = (const uint4*)g_mesh16 + (size_t)i2 * 4;
        #pragma unroll
        for (int kg = 0; kg < 4; ++kg) { x0[kg] = m0[kg]; x1[kg] = m1[kg]; x2[kg] = m2[kg]; }
    };

    // interp staged rows (waits row loads) -> fragment-ordered LDS
    auto write_lds = [&](int s) {
        int nch = (s < NSEC - 1) ? SECC : 1;
        if (clt >= nch) return;
        #pragma unroll
        for (int kg = 0; kg < 4; ++kg) {
            union { uint4 v; __half2 h[4]; } a0, a1, a2, o;
            a0.v = x0[kg]; a1.v = x1[kg]; a2.v = x2[kg];
            #pragma unroll
            for (int q = 0; q < 4; ++q)
                o.h[q] = __hfma2(a0.h[q], sw0,
                         __hfma2(a1.h[q], sw1, __hmul2(a2.h[q], sw2)));
            *(uint4*)(dst0 + kg * 128) = o.v;
        }
    };

    // ---- pipeline prologue ----
    bary_issue(0);
    rows_issue(0);       // waits bary(0), issues rows(0)
    bary_issue(1);

    for (int s = 0; s < NSEC; ++s) {
        __syncthreads();                 // previous MFMA done reading LDS
        write_lds(s);                    // waits rows(s), writes LDS
        __syncthreads();                 // LDS visible to all waves
        rows_issue(s + 1);               // bary(s+1) already arrived; rows fly over MFMA(s)
        bary_issue(s + 2);               // bary flies over MFMA(s) + MFMA(s+1)

        // ---- MFMA over this section's chunks; B (hi+lo) reused for 2 row-tiles ----
        const int nch = (s < NSEC - 1) ? SECC : 1;
        const int sec = s * SECC;
        #pragma unroll 2
        for (int c = 0; c < nch; ++c) {
            int ch = sec + c;
            size_t bo = ((size_t)(ch * 16 + wv * 4) * 64 + lane) * 8;
            const f16x8* bh = (const f16x8*)&g_bhi[bo];
            const f16x8* bl = (const f16x8*)&g_blo[bo];
            f16x8 bhj[4], blj[4];
            #pragma unroll
            for (int j = 0; j < 4; ++j) { bhj[j] = bh[j * 64]; blj[j] = bl[j * 64]; }
            #pragma unroll
            for (int rt = 0; rt < 2; ++rt) {
                f16x8 ah = *(const f16x8*)&Alds[((size_t)(c * 2 + rt) * 64 + lane) * 8];
                #pragma unroll
                for (int j = 0; j < 4; ++j) {
                    acc[rt][j] = __builtin_amdgcn_mfma_f32_16x16x32_f16(ah, bhj[j], acc[rt][j], 0, 0, 0);
                    acc[rt][j] = __builtin_amdgcn_mfma_f32_16x16x32_f16(ah, blj[j], acc[rt][j], 0, 0, 0);
                }
            }
        }
    }

    // ---- epilogue: C/D layout col=lane&15, row=(lane>>4)*4+reg [m89] ----
    const int col = lane & 15, rg = lane >> 4;
    #pragma unroll
    for (int j = 0; j < 4; ++j) {
        int c = (wv * 4 + j) * 16 + col;
        float bv = ld(bias, c & 31, isf32);
        #pragma unroll
        for (int rt = 0; rt < 2; ++rt) {
            #pragma unroll
            for (int r = 0; r < 4; ++r) {
                int row = n0 + rt * 16 + rg * 4 + r;
                if (row < N_MESH) {
                    float v = acc[rt][j][r] + bv;
                    v = v > 0.f ? v : 0.f;
                    size_t oi = (size_t)row * OT + c;
                    if (isf32) ((float*)out)[oi] = v;
                    else       ((u16*)out)[oi]   = f2bf(v);
                }
            }
        }
    }
}

extern "C" void kernel_launch(void* const* d_in, const int* in_sizes, int n_in,
                              void* d_out, int out_size, void* d_ws, size_t ws_size,
                              hipStream_t stream) {
    const void* mesh  = d_in[0];
    const void* bary  = d_in[1];
    const void* Wself = d_in[2];
    const void* Wn    = d_in[3];
    const void* bias  = d_in[4];
    const void* ker   = d_in[5];
    (void)in_sizes; (void)n_in; (void)out_size; (void)d_ws; (void)ws_size;

    detect_kernel<<<1, 256, 0, stream>>>(mesh);

    prep_kernel<<<MESH16_BLOCKS + WEFF_BLOCKS, 256, 0, stream>>>(mesh, Wn, Wself, ker);

    ConvIntrinsic_17102559772776_kernel<<<NBLK, 256, 0, stream>>>(mesh, bary, bias, d_out);
}

// Round 8
// 267.179 us; speedup vs baseline: 1.2171x; 1.2171x over previous
//
#include <hip/hip_runtime.h>
#include <hip/hip_fp16.h>

typedef unsigned short u16;
typedef unsigned int   u32;

#define N_MESH 50000
#define RA     40      // R*A
#define F_     32
#define OT     256     // O*T
#define KSELF  1280    // RA*F
#define KTOT   1312    // RA*F + F  (= 41*32 exactly)
#define NCH    41      // K chunks of 32
#define GN     32      // mesh rows per block (2 row-tiles of 16)
#define NBLK   1563    // ceil(50000/32); last block has 16 valid rows
#define SECC   8       // chunks per LDS section (sections: 8,8,8,8,8,1)
#define MESH16_BLOCKS 782   // ceil(200000/256)
#define WEFF_BLOCKS   1312  // 256*1312/256

using f32x4 = __attribute__((ext_vector_type(4))) float;
using f16x8 = __attribute__((ext_vector_type(8))) _Float16;   // 8 f16 (4 VGPRs)

// Device-global scratch / flags (no dependence on ws_size).
__device__ __align__(16) u16 g_bhi[NCH * 16 * 64 * 8];      // B frags hi (f16), 672 KB
__device__ __align__(16) u16 g_blo[NCH * 16 * 64 * 8];      // B frags lo (f16), 672 KB
__device__ __align__(16) u16 g_mesh16[N_MESH * F_];         // fp16 mesh shadow, 3.2 MB
__device__ int g_isf32;

__device__ __forceinline__ float bf2f(u16 u) {
    union { u32 i; float f; } v; v.i = ((u32)u) << 16; return v.f;
}
__device__ __forceinline__ u16 f2bf(float f) {
    union { float f; u32 i; } v; v.f = f; u32 u = v.i;
    return (u16)((u + 0x7FFFu + ((u >> 16) & 1u)) >> 16);   // RNE
}
__device__ __forceinline__ float ld(const void* p, int i, int isf32) {
    return isf32 ? ((const float*)p)[i] : bf2f(((const u16*)p)[i]);
}

// ---------------------------------------------------------------------------
// Dtype probe (parallelized): decode first 4096 u16 of mesh_signal as bf16.
// ---------------------------------------------------------------------------
__global__ void detect_kernel(const void* mesh) {
    __shared__ int s_weird;
    if (threadIdx.x == 0) s_weird = 0;
    __syncthreads();
    const u16* p = (const u16*)mesh;
    int w = 0;
    for (int j = threadIdx.x * 16; j < threadIdx.x * 16 + 16; ++j) {
        float v = bf2f(p[j]);
        float a = v < 0.f ? -v : v;
        if (!(a <= 1.0e6f)) ++w;
        else if (a > 0.f && a < 1.0e-30f) ++w;
    }
    atomicAdd(&s_weird, w);
    __syncthreads();
    if (threadIdx.x == 0) g_isf32 = (s_weird > 100) ? 1 : 0;
}

// ---------------------------------------------------------------------------
// Fused prep kernel:
//  blocks [0, MESH16_BLOCKS)      : fp16 mesh shadow (3.2 MB, L2-resident;
//                                   round 5 proved: FETCH 273MB -> 107MB)
//  blocks [MESH16_BLOCKS, +WEFF)  : Weff + f16 hi/lo B-fragment pack.
//   k <  1280 : w = sum_ra kernel[ra][k>>5] * W_neighbor[t][r][(a+o)&7][k&31]
//   k >= 1280 : w = W_self[t][k-1280]
//   B-frag layout (mfma_f32_16x16x32 B): lane l, elem e <-> B[k=(l>>4)*8+e][col=l&15]
// ---------------------------------------------------------------------------
__global__ void prep_kernel(const void* __restrict__ mesh,
                            const void* __restrict__ Wn,
                            const void* __restrict__ Wself,
                            const void* __restrict__ ker) {
    const int isf32 = g_isf32;
    if (blockIdx.x < MESH16_BLOCKS) {
        int i = blockIdx.x * 256 + threadIdx.x;   // one thread per 8 elems
        if (i >= N_MESH * F_ / 8) return;
        union { uint4 v; _Float16 h[8]; } o;
        #pragma unroll
        for (int j = 0; j < 8; ++j)
            o.h[j] = (_Float16)ld(mesh, i * 8 + j, isf32);
        *((uint4*)g_mesh16 + i) = o.v;
    } else {
        int e = (blockIdx.x - MESH16_BLOCKS) * 256 + threadIdx.x;
        if (e >= OT * KTOT) return;
        int c = e / KTOT;
        int k = e - c * KTOT;
        int t = c & 31;
        float acc = 0.f;
        if (k < KSELF) {
            int xy = k >> 5, f = k & 31;
            int o = c >> 5;
            for (int ra = 0; ra < RA; ++ra) {
                int r = ra >> 3, a = ra & 7;
                int a2 = (a + o) & 7;
                acc += ld(ker, ra * RA + xy, isf32) *
                       ld(Wn, t * (5 * 8 * F_) + r * (8 * F_) + a2 * F_ + f, isf32);
            }
        } else {
            acc = ld(Wself, t * F_ + (k - KSELF), isf32);
        }
        int ch = k >> 5;
        int kg = (k >> 3) & 3;
        int el = k & 7;
        int nt = c >> 4, col = c & 15;
        size_t fi = ((size_t)(ch * 16 + nt) * 64 + (kg * 16 + col)) * 8 + el;
        union { _Float16 h; u16 u; } H, L;
        H.h = (_Float16)acc;
        L.h = (_Float16)(acc - (float)H.h);
        g_bhi[fi] = H.u;
        g_blo[fi] = L.u;
    }
}

// ---------------------------------------------------------------------------
// Main kernel. Per block: 32 mesh rows (2 row-tiles) x 256 outputs.
// This is the round-5 structure (best measured: 212us) with round-6 math:
//   phase 1: packed-f16 interp (__hfma2 on fp16 shadow dwords) -> fragment-
//            ordered LDS, single f16 A. One task per thread (8 chunks x 32
//            rows = 256), straight-line, no register pipeline (r7 regressed).
//   phase 2: 2x MFMA f16 per (rt,j): A*Bhi + A*Blo (B hi/lo ~ 22-bit Weff).
// LDS = 16 KB (single f16 A buffer). launch_bounds(256,4): r2/r5 proved the
// compiler lands ~60-64 VGPR here. NOT (256,8): forced 32 VGPR + acc spill
// (round 3: 714us). NOT GN=64: acc doubles, occupancy 35->25 (round 6).
// ---------------------------------------------------------------------------
__global__ __launch_bounds__(256, 4)
void ConvIntrinsic_17102559772776_kernel(const void* __restrict__ mesh,
                                         const void* __restrict__ bary,
                                         const void* __restrict__ bias,
                                         void* __restrict__ out) {
    __shared__ __align__(16) u16 Alds[SECC * 2 * 64 * 8];   // 16 KB (f16 bits)

    const int tid   = threadIdx.x;
    const int n0    = blockIdx.x * GN;
    const int isf32 = g_isf32;
    const int lane  = tid & 63;
    const int wv    = tid >> 6;    // 0..3 : wave owns N-tiles wv*4 .. wv*4+3
    const int clt   = tid >> 5;    // phase-1 chunk-local 0..7 (active if < nch)
    const int tn    = tid & 31;    // phase-1 row within block
    const int gn    = n0 + tn;
    const int rt1   = tn >> 4, lr = tn & 15;
    u16* const dst0 = Alds + ((size_t)(clt * 2 + rt1) * 64 + lr) * 8;  // +kg*128

    f32x4 acc[2][4];
    #pragma unroll
    for (int rt = 0; rt < 2; ++rt)
        #pragma unroll
        for (int j = 0; j < 4; ++j) acc[rt][j] = (f32x4){0.f, 0.f, 0.f, 0.f};

    for (int sec = 0; sec < NCH; sec += SECC) {
        int nch = NCH - sec; if (nch > SECC) nch = SECC;

        // ---- phase 1: packed-f16 gather+interp -> fragment-ordered LDS ----
        if (clt < nch) {
            const int ch = sec + clt;
            if (gn >= N_MESH) {
                #pragma unroll
                for (int kg = 0; kg < 4; ++kg)
                    *(uint4*)(dst0 + kg * 128) = make_uint4(0, 0, 0, 0);
            } else if (ch < RA) {
                float fi0, w0, fi1, w1, fi2, w2;
                if (isf32) {
                    const float* bp = (const float*)bary + (size_t)gn * (RA * 6) + ch * 6;
                    fi0 = bp[0]; w0 = bp[1]; fi1 = bp[2]; w1 = bp[3]; fi2 = bp[4]; w2 = bp[5];
                } else {
                    const u16* bp = (const u16*)bary + (size_t)gn * (RA * 6) + ch * 6;
                    fi0 = bf2f(bp[0]); w0 = bf2f(bp[1]);
                    fi1 = bf2f(bp[2]); w1 = bf2f(bp[3]);
                    fi2 = bf2f(bp[4]); w2 = bf2f(bp[5]);
                }
                int i0 = (int)fi0, i1 = (int)fi1, i2 = (int)fi2;
                i0 = i0 < 0 ? 0 : (i0 > N_MESH - 1 ? N_MESH - 1 : i0);
                i1 = i1 < 0 ? 0 : (i1 > N_MESH - 1 ? N_MESH - 1 : i1);
                i2 = i2 < 0 ? 0 : (i2 > N_MESH - 1 ? N_MESH - 1 : i2);
                const uint4* m0 = (const uint4*)g_mesh16 + (size_t)i0 * 4;
                const uint4* m1 = (const uint4*)g_mesh16 + (size_t)i1 * 4;
                const uint4* m2 = (const uint4*)g_mesh16 + (size_t)i2 * 4;
                __half2 w0h = __float2half2_rn(w0);
                __half2 w1h = __float2half2_rn(w1);
                __half2 w2h = __float2half2_rn(w2);
                #pragma unroll
                for (int kg = 0; kg < 4; ++kg) {
                    union { uint4 v; __half2 h[4]; } x0, x1, x2, o;
                    x0.v = m0[kg]; x1.v = m1[kg]; x2.v = m2[kg];
                    #pragma unroll
                    for (int q = 0; q < 4; ++q)
                        o.h[q] = __hfma2(x0.h[q], w0h,
                                 __hfma2(x1.h[q], w1h, __hmul2(x2.h[q], w2h)));
                    *(uint4*)(dst0 + kg * 128) = o.v;
                }
            } else {
                // self chunk (k=1280..1311): straight fp16 row copy
                const uint4* ms = (const uint4*)g_mesh16 + (size_t)gn * 4;
                #pragma unroll
                for (int kg = 0; kg < 4; ++kg)
                    *(uint4*)(dst0 + kg * 128) = ms[kg];
            }
        }
        __syncthreads();

        // ---- phase 2: MFMA; B (hi+lo) reused across 2 row-tiles ----
        #pragma unroll 2
        for (int c = 0; c < nch; ++c) {
            int ch = sec + c;
            size_t bo = ((size_t)(ch * 16 + wv * 4) * 64 + lane) * 8;
            const f16x8* bh = (const f16x8*)&g_bhi[bo];
            const f16x8* bl = (const f16x8*)&g_blo[bo];
            f16x8 bhj[4], blj[4];
            #pragma unroll
            for (int j = 0; j < 4; ++j) { bhj[j] = bh[j * 64]; blj[j] = bl[j * 64]; }
            #pragma unroll
            for (int rt = 0; rt < 2; ++rt) {
                f16x8 ah = *(const f16x8*)&Alds[((size_t)(c * 2 + rt) * 64 + lane) * 8];
                #pragma unroll
                for (int j = 0; j < 4; ++j) {
                    acc[rt][j] = __builtin_amdgcn_mfma_f32_16x16x32_f16(ah, bhj[j], acc[rt][j], 0, 0, 0);
                    acc[rt][j] = __builtin_amdgcn_mfma_f32_16x16x32_f16(ah, blj[j], acc[rt][j], 0, 0, 0);
                }
            }
        }
        __syncthreads();
    }

    // ---- epilogue: C/D layout col=lane&15, row=(lane>>4)*4+reg [m89] ----
    const int col = lane & 15, rg = lane >> 4;
    #pragma unroll
    for (int j = 0; j < 4; ++j) {
        int c = (wv * 4 + j) * 16 + col;
        float bv = ld(bias, c & 31, isf32);
        #pragma unroll
        for (int rt = 0; rt < 2; ++rt) {
            #pragma unroll
            for (int r = 0; r < 4; ++r) {
                int row = n0 + rt * 16 + rg * 4 + r;
                if (row < N_MESH) {
                    float v = acc[rt][j][r] + bv;
                    v = v > 0.f ? v : 0.f;
                    size_t oi = (size_t)row * OT + c;
                    if (isf32) ((float*)out)[oi] = v;
                    else       ((u16*)out)[oi]   = f2bf(v);
                }
            }
        }
    }
}

extern "C" void kernel_launch(void* const* d_in, const int* in_sizes, int n_in,
                              void* d_out, int out_size, void* d_ws, size_t ws_size,
                              hipStream_t stream) {
    const void* mesh  = d_in[0];
    const void* bary  = d_in[1];
    const void* Wself = d_in[2];
    const void* Wn    = d_in[3];
    const void* bias  = d_in[4];
    const void* ker   = d_in[5];
    (void)in_sizes; (void)n_in; (void)out_size; (void)d_ws; (void)ws_size;

    detect_kernel<<<1, 256, 0, stream>>>(mesh);

    prep_kernel<<<MESH16_BLOCKS + WEFF_BLOCKS, 256, 0, stream>>>(mesh, Wn, Wself, ker);

    ConvIntrinsic_17102559772776_kernel<<<NBLK, 256, 0, stream>>>(mesh, bary, bias, d_out);
}

// Round 9
// 230.177 us; speedup vs baseline: 1.4128x; 1.1608x over previous
//
#include <hip/hip_runtime.h>
#include <hip/hip_fp16.h>

typedef unsigned short u16;
typedef unsigned int   u32;

#define N_MESH 50000
#define RA     40      // R*A
#define F_     32
#define OT     256     // O*T
#define KSELF  1280    // RA*F
#define KTOT   1312    // RA*F + F  (= 41*32 exactly)
#define NCH    41      // K chunks of 32
#define GN     32      // mesh rows per block (2 row-tiles of 16)
#define NBLK   1563    // ceil(50000/32); last block has 16 valid rows
#define SECC   8       // chunks per LDS section (sections: 8,8,8,8,8,1)
#define MESH16_BLOCKS 782   // ceil(200000/256)
#define WEFF_BLOCKS   1312  // 256*1312/256

using f32x4 = __attribute__((ext_vector_type(4))) float;
using f16x8 = __attribute__((ext_vector_type(8))) _Float16;   // 8 f16 (4 VGPRs)

// Device-global scratch / flags (no dependence on ws_size).
// Single-f16 B (no lo residual): B(672KB) + mesh16(3.2MB) = 3.87MB fits one
// XCD's 4MB L2 (hi+lo made the set 4.5MB -> evictions). Error budget: f16
// rel 2^-11 on Weff (sigma~0.1) -> output err ~3e-3 max, well under the bf16
// output quantization step (absmax floor 0.03125).
__device__ __align__(16) u16 g_bhi[NCH * 16 * 64 * 8];      // B frags (f16), 672 KB
__device__ __align__(16) u16 g_mesh16[N_MESH * F_];         // fp16 mesh shadow, 3.2 MB
__device__ int g_isf32;

__device__ __forceinline__ float bf2f(u16 u) {
    union { u32 i; float f; } v; v.i = ((u32)u) << 16; return v.f;
}
__device__ __forceinline__ u16 f2bf(float f) {
    union { float f; u32 i; } v; v.f = f; u32 u = v.i;
    return (u16)((u + 0x7FFFu + ((u >> 16) & 1u)) >> 16);   // RNE
}
__device__ __forceinline__ float ld(const void* p, int i, int isf32) {
    return isf32 ? ((const float*)p)[i] : bf2f(((const u16*)p)[i]);
}

// ---------------------------------------------------------------------------
// Dtype probe (parallelized): decode first 4096 u16 of mesh_signal as bf16.
// ---------------------------------------------------------------------------
__global__ void detect_kernel(const void* mesh) {
    __shared__ int s_weird;
    if (threadIdx.x == 0) s_weird = 0;
    __syncthreads();
    const u16* p = (const u16*)mesh;
    int w = 0;
    for (int j = threadIdx.x * 16; j < threadIdx.x * 16 + 16; ++j) {
        float v = bf2f(p[j]);
        float a = v < 0.f ? -v : v;
        if (!(a <= 1.0e6f)) ++w;
        else if (a > 0.f && a < 1.0e-30f) ++w;
    }
    atomicAdd(&s_weird, w);
    __syncthreads();
    if (threadIdx.x == 0) g_isf32 = (s_weird > 100) ? 1 : 0;
}

// ---------------------------------------------------------------------------
// Fused prep kernel:
//  blocks [0, MESH16_BLOCKS)      : fp16 mesh shadow (3.2 MB, L2-resident;
//                                   round 5 proved: FETCH 273MB -> 107MB)
//  blocks [MESH16_BLOCKS, +WEFF)  : Weff -> single-f16 B-fragment pack.
//   k <  1280 : w = sum_ra kernel[ra][k>>5] * W_neighbor[t][r][(a+o)&7][k&31]
//   k >= 1280 : w = W_self[t][k-1280]
//   B-frag layout (mfma_f32_16x16x32 B): lane l, elem e <-> B[k=(l>>4)*8+e][col=l&15]
// ---------------------------------------------------------------------------
__global__ void prep_kernel(const void* __restrict__ mesh,
                            const void* __restrict__ Wn,
                            const void* __restrict__ Wself,
                            const void* __restrict__ ker) {
    const int isf32 = g_isf32;
    if (blockIdx.x < MESH16_BLOCKS) {
        int i = blockIdx.x * 256 + threadIdx.x;   // one thread per 8 elems
        if (i >= N_MESH * F_ / 8) return;
        union { uint4 v; _Float16 h[8]; } o;
        #pragma unroll
        for (int j = 0; j < 8; ++j)
            o.h[j] = (_Float16)ld(mesh, i * 8 + j, isf32);
        *((uint4*)g_mesh16 + i) = o.v;
    } else {
        int e = (blockIdx.x - MESH16_BLOCKS) * 256 + threadIdx.x;
        if (e >= OT * KTOT) return;
        int c = e / KTOT;
        int k = e - c * KTOT;
        int t = c & 31;
        float acc = 0.f;
        if (k < KSELF) {
            int xy = k >> 5, f = k & 31;
            int o = c >> 5;
            for (int ra = 0; ra < RA; ++ra) {
                int r = ra >> 3, a = ra & 7;
                int a2 = (a + o) & 7;
                acc += ld(ker, ra * RA + xy, isf32) *
                       ld(Wn, t * (5 * 8 * F_) + r * (8 * F_) + a2 * F_ + f, isf32);
            }
        } else {
            acc = ld(Wself, t * F_ + (k - KSELF), isf32);
        }
        int ch = k >> 5;
        int kg = (k >> 3) & 3;
        int el = k & 7;
        int nt = c >> 4, col = c & 15;
        size_t fi = ((size_t)(ch * 16 + nt) * 64 + (kg * 16 + col)) * 8 + el;
        union { _Float16 h; u16 u; } H;
        H.h = (_Float16)acc;
        g_bhi[fi] = H.u;
    }
}

// ---------------------------------------------------------------------------
// Main kernel. Per block: 32 mesh rows (2 row-tiles) x 256 outputs.
// Round-8 structure (best measured: 177us) with single-pass B:
//   phase 1: packed-f16 interp (__hfma2 on fp16 shadow dwords) -> fragment-
//            ordered LDS, single f16 A. One task per thread, straight-line,
//            no register pipeline (r7 regressed).
//   phase 2: 1x MFMA f16 per (rt,j) (B single f16; halves MFMA + B L2 bytes
//            vs the hi/lo split, and makes B+mesh16 fit one XCD L2).
// LDS = 16 KB. launch_bounds(256,4): compiler lands ~60 VGPR here. NOT
// (256,8): forced 32 VGPR + acc spill (round 3: 714us). NOT GN=64: acc
// doubles, occupancy 35->25 (round 6).
// ---------------------------------------------------------------------------
__global__ __launch_bounds__(256, 4)
void ConvIntrinsic_17102559772776_kernel(const void* __restrict__ mesh,
                                         const void* __restrict__ bary,
                                         const void* __restrict__ bias,
                                         void* __restrict__ out) {
    __shared__ __align__(16) u16 Alds[SECC * 2 * 64 * 8];   // 16 KB (f16 bits)

    const int tid   = threadIdx.x;
    const int n0    = blockIdx.x * GN;
    const int isf32 = g_isf32;
    const int lane  = tid & 63;
    const int wv    = tid >> 6;    // 0..3 : wave owns N-tiles wv*4 .. wv*4+3
    const int clt   = tid >> 5;    // phase-1 chunk-local 0..7 (active if < nch)
    const int tn    = tid & 31;    // phase-1 row within block
    const int gn    = n0 + tn;
    const int rt1   = tn >> 4, lr = tn & 15;
    u16* const dst0 = Alds + ((size_t)(clt * 2 + rt1) * 64 + lr) * 8;  // +kg*128

    f32x4 acc[2][4];
    #pragma unroll
    for (int rt = 0; rt < 2; ++rt)
        #pragma unroll
        for (int j = 0; j < 4; ++j) acc[rt][j] = (f32x4){0.f, 0.f, 0.f, 0.f};

    for (int sec = 0; sec < NCH; sec += SECC) {
        int nch = NCH - sec; if (nch > SECC) nch = SECC;

        // ---- phase 1: packed-f16 gather+interp -> fragment-ordered LDS ----
        if (clt < nch) {
            const int ch = sec + clt;
            if (gn >= N_MESH) {
                #pragma unroll
                for (int kg = 0; kg < 4; ++kg)
                    *(uint4*)(dst0 + kg * 128) = make_uint4(0, 0, 0, 0);
            } else if (ch < RA) {
                float fi0, w0, fi1, w1, fi2, w2;
                if (isf32) {
                    const float* bp = (const float*)bary + (size_t)gn * (RA * 6) + ch * 6;
                    fi0 = bp[0]; w0 = bp[1]; fi1 = bp[2]; w1 = bp[3]; fi2 = bp[4]; w2 = bp[5];
                } else {
                    const u16* bp = (const u16*)bary + (size_t)gn * (RA * 6) + ch * 6;
                    fi0 = bf2f(bp[0]); w0 = bf2f(bp[1]);
                    fi1 = bf2f(bp[2]); w1 = bf2f(bp[3]);
                    fi2 = bf2f(bp[4]); w2 = bf2f(bp[5]);
                }
                int i0 = (int)fi0, i1 = (int)fi1, i2 = (int)fi2;
                i0 = i0 < 0 ? 0 : (i0 > N_MESH - 1 ? N_MESH - 1 : i0);
                i1 = i1 < 0 ? 0 : (i1 > N_MESH - 1 ? N_MESH - 1 : i1);
                i2 = i2 < 0 ? 0 : (i2 > N_MESH - 1 ? N_MESH - 1 : i2);
                const uint4* m0 = (const uint4*)g_mesh16 + (size_t)i0 * 4;
                const uint4* m1 = (const uint4*)g_mesh16 + (size_t)i1 * 4;
                const uint4* m2 = (const uint4*)g_mesh16 + (size_t)i2 * 4;
                __half2 w0h = __float2half2_rn(w0);
                __half2 w1h = __float2half2_rn(w1);
                __half2 w2h = __float2half2_rn(w2);
                #pragma unroll
                for (int kg = 0; kg < 4; ++kg) {
                    union { uint4 v; __half2 h[4]; } x0, x1, x2, o;
                    x0.v = m0[kg]; x1.v = m1[kg]; x2.v = m2[kg];
                    #pragma unroll
                    for (int q = 0; q < 4; ++q)
                        o.h[q] = __hfma2(x0.h[q], w0h,
                                 __hfma2(x1.h[q], w1h, __hmul2(x2.h[q], w2h)));
                    *(uint4*)(dst0 + kg * 128) = o.v;
                }
            } else {
                // self chunk (k=1280..1311): straight fp16 row copy
                const uint4* ms = (const uint4*)g_mesh16 + (size_t)gn * 4;
                #pragma unroll
                for (int kg = 0; kg < 4; ++kg)
                    *(uint4*)(dst0 + kg * 128) = ms[kg];
            }
        }
        __syncthreads();

        // ---- phase 2: MFMA; B reused across 2 row-tiles ----
        #pragma unroll 2
        for (int c = 0; c < nch; ++c) {
            int ch = sec + c;
            size_t bo = ((size_t)(ch * 16 + wv * 4) * 64 + lane) * 8;
            const f16x8* bh = (const f16x8*)&g_bhi[bo];
            f16x8 bhj[4];
            #pragma unroll
            for (int j = 0; j < 4; ++j) bhj[j] = bh[j * 64];
            #pragma unroll
            for (int rt = 0; rt < 2; ++rt) {
                f16x8 ah = *(const f16x8*)&Alds[((size_t)(c * 2 + rt) * 64 + lane) * 8];
                #pragma unroll
                for (int j = 0; j < 4; ++j)
                    acc[rt][j] = __builtin_amdgcn_mfma_f32_16x16x32_f16(ah, bhj[j], acc[rt][j], 0, 0, 0);
            }
        }
        __syncthreads();
    }

    // ---- epilogue: C/D layout col=lane&15, row=(lane>>4)*4+reg [m89] ----
    const int col = lane & 15, rg = lane >> 4;
    #pragma unroll
    for (int j = 0; j < 4; ++j) {
        int c = (wv * 4 + j) * 16 + col;
        float bv = ld(bias, c & 31, isf32);
        #pragma unroll
        for (int rt = 0; rt < 2; ++rt) {
            #pragma unroll
            for (int r = 0; r < 4; ++r) {
                int row = n0 + rt * 16 + rg * 4 + r;
                if (row < N_MESH) {
                    float v = acc[rt][j][r] + bv;
                    v = v > 0.f ? v : 0.f;
                    size_t oi = (size_t)row * OT + c;
                    if (isf32) ((float*)out)[oi] = v;
                    else       ((u16*)out)[oi]   = f2bf(v);
                }
            }
        }
    }
}

extern "C" void kernel_launch(void* const* d_in, const int* in_sizes, int n_in,
                              void* d_out, int out_size, void* d_ws, size_t ws_size,
                              hipStream_t stream) {
    const void* mesh  = d_in[0];
    const void* bary  = d_in[1];
    const void* Wself = d_in[2];
    const void* Wn    = d_in[3];
    const void* bias  = d_in[4];
    const void* ker   = d_in[5];
    (void)in_sizes; (void)n_in; (void)out_size; (void)d_ws; (void)ws_size;

    detect_kernel<<<1, 256, 0, stream>>>(mesh);

    prep_kernel<<<MESH16_BLOCKS + WEFF_BLOCKS, 256, 0, stream>>>(mesh, Wn, Wself, ker);

    ConvIntrinsic_17102559772776_kernel<<<NBLK, 256, 0, stream>>>(mesh, bary, bias, d_out);
}